// Round 8
// baseline (192.566 us; speedup 1.0000x reference)
//
#include <hip/hip_runtime.h>

#define CNT    2048
#define TPB    256
#define RPB    4            // waves per block; one row per wave
#define NCHUNK 8            // chunks per row
#define CSTEP  256          // steps per chunk
#define GFL    768          // gyro floats per chunk (CSTEP*3)
#define BUFF   1028         // floats per buffer: 768 gyro + 256 ts + 4 pad

struct Q { float w, x, y, z; };

__device__ __forceinline__ Q qmul(const Q a, const Q b) {
    Q o;
    o.w = fmaf(a.w, b.w, fmaf(-a.x, b.x, fmaf(-a.y, b.y, -a.z * b.z)));
    o.x = fmaf(a.w, b.x, fmaf( a.x, b.w, fmaf( a.y, b.z, -a.z * b.y)));
    o.y = fmaf(a.w, b.y, fmaf(-a.x, b.z, fmaf( a.y, b.w,  a.z * b.x)));
    o.z = fmaf(a.w, b.z, fmaf( a.x, b.y, fmaf(-a.y, b.x,  a.z * b.w)));
    return o;
}

__device__ __forceinline__ Q qmul1(const Q a, const float bx, const float by, const float bz) {
    Q o;
    o.w = fmaf(-a.x, bx, fmaf(-a.y, by, fmaf(-a.z, bz, a.w)));
    o.x = fmaf( a.w, bx, fmaf( a.y, bz, fmaf(-a.z, by, a.x)));
    o.y = fmaf( a.w, by, fmaf(-a.x, bz, fmaf( a.z, bx, a.y)));
    o.z = fmaf( a.w, bz, fmaf( a.x, by, fmaf(-a.y, bx, a.z)));
    return o;
}

__device__ __forceinline__ float prelu(const float x, const float a, const float one_m_a) {
    return fmaf(one_m_a, fmaxf(x, 0.0f), a * x);
}

// async global->LDS DMA, 16B per lane. LDS dest = UNIFORM base (HW adds lane*16);
// global src is per-lane. Counted by vmcnt. No VGPR round-trip, cannot be re-sunk.
__device__ __forceinline__ void dma16(const float* g, float* l) {
    __builtin_amdgcn_global_load_lds(
        (const __attribute__((address_space(1))) void*)g,
        (__attribute__((address_space(3))) void*)l,
        16, 0, 0);
}

#define WAITV(n) do { asm volatile("s_waitcnt vmcnt(" #n ")" ::: "memory"); \
                      __builtin_amdgcn_sched_barrier(0); } while (0)

__global__ __launch_bounds__(TPB) void quat_scan_kernel(
    const float* __restrict__ ts,    // (B, CNT)
    const float* __restrict__ gyro,  // (B, CNT, 3)
    const float* __restrict__ sq,    // (B, 4)
    const float* __restrict__ W1, const float* __restrict__ b1, const float* __restrict__ a1p,
    const float* __restrict__ W2, const float* __restrict__ b2, const float* __restrict__ a2p,
    float* __restrict__ out,         // (B, 4)
    const int B)
{
    __shared__ float lds[RPB][2][BUFF];   // 32,896 B per block

    const int lane = threadIdx.x & 63;
    const int wid  = threadIdx.x >> 6;
    const int row  = blockIdx.x * RPB + wid;
    if (row >= B) return;                 // wave-uniform (never taken at B=4096)

    // ---- small params: wave-uniform scalar loads -> SGPRs
    float w1[9], w2[9], bb1[3], bb2[3];
    #pragma unroll
    for (int i = 0; i < 9; ++i) { w1[i] = W1[i]; w2[i] = W2[i]; }
    #pragma unroll
    for (int i = 0; i < 3; ++i) { bb1[i] = b1[i]; bb2[i] = b2[i]; }
    const float a1 = a1p[0], a2 = a2p[0];
    const float oma1 = 1.0f - a1, oma2 = 1.0f - a2;

    auto gfv = [&](const float vx, const float vy, const float vz,
                   float& gx, float& gy, float& gz) {
        float h0 = fmaf(w1[0], vx, fmaf(w1[1], vy, fmaf(w1[2], vz, bb1[0])));
        float h1 = fmaf(w1[3], vx, fmaf(w1[4], vy, fmaf(w1[5], vz, bb1[1])));
        float h2 = fmaf(w1[6], vx, fmaf(w1[7], vy, fmaf(w1[8], vz, bb1[2])));
        h0 = prelu(h0, a1, oma1);
        h1 = prelu(h1, a1, oma1);
        h2 = prelu(h2, a1, oma1);
        float u0 = fmaf(w2[0], h0, fmaf(w2[1], h1, fmaf(w2[2], h2, bb2[0])));
        float u1 = fmaf(w2[3], h0, fmaf(w2[4], h1, fmaf(w2[5], h2, bb2[1])));
        float u2 = fmaf(w2[6], h0, fmaf(w2[7], h1, fmaf(w2[8], h2, bb2[2])));
        gx = prelu(u0, a2, oma2) + vx;
        gy = prelu(u1, a2, oma2) + vy;
        gz = prelu(u2, a2, oma2) + vz;
    };

    const float* grow = gyro + (size_t)row * (CNT * 3);
    const float* trow = ts   + (size_t)row * CNT;
    float* buf0 = &lds[wid][0][0];
    float* buf1 = &lds[wid][1][0];

    // DMA one chunk: 3x 1KB gyro + 1x 1KB ts, all perfectly coalesced (16 lines/instr)
    auto issue = [&](const int c, float* bp) {
        const float* gs = grow + c * GFL + lane * 4;
        dma16(gs +   0, bp +   0);
        dma16(gs + 256, bp + 256);
        dma16(gs + 512, bp + 512);
        dma16(trow + c * CSTEP + lane * 4, bp + GFL);
    };

    issue(0, buf0);
    issue(1, buf1);          // 8 outstanding

    Q acc = {1.0f, 0.0f, 0.0f, 0.0f};

    WAITV(4);                // chunk 0 landed (chunk 1 still in flight)

    for (int c = 0; c < NCHUNK; ++c) {
        float* cur = (c & 1) ? buf1 : buf0;   // holds chunk c (guaranteed landed)
        float* oth = (c & 1) ? buf0 : buf1;   // holds chunk c+1 (in flight)

        // lane l owns steps 4l..4l+3 of this chunk. LDS reads are conflict-free:
        // gyro b128 dword-addr 12l+4k -> 12l mod 32 covers all 8 bank groups.
        const float4* gb = (const float4*)cur;
        const float4* tb = (const float4*)(cur + GFL);
        const float4 Wa = gb[3 * lane + 0];
        const float4 Wb = gb[3 * lane + 1];
        const float4 Wc = gb[3 * lane + 2];
        const float4 Wd = gb[3 * lane + 3];   // lane 63: ts region (finite junk, unused/pad)
        const float4 Ta = tb[lane];
        const float4 Tb = tb[lane + 1];       // lane 63: pad floats (finite junk, overridden)

        Q q = {1.0f, 0.0f, 0.0f, 0.0f};
        float ax, ay, az, bx, by, bz;
        gfv(Wa.x, Wa.y, Wa.z, ax, ay, az);
        // u=0..2: fully inside cur
        gfv(Wa.w, Wb.x, Wb.y, bx, by, bz);
        { const float s = 0.25f * (Ta.y - Ta.x);
          q = qmul1(q, (ax + bx) * s, (ay + by) * s, (az + bz) * s); }
        ax = bx; ay = by; az = bz;
        gfv(Wb.z, Wb.w, Wc.x, bx, by, bz);
        { const float s = 0.25f * (Ta.z - Ta.y);
          q = qmul1(q, (ax + bx) * s, (ay + by) * s, (az + bz) * s); }
        ax = bx; ay = by; az = bz;
        gfv(Wc.y, Wc.z, Wc.w, bx, by, bz);
        { const float s = 0.25f * (Ta.w - Ta.z);
          q = qmul1(q, (ax + bx) * s, (ay + by) * s, (az + bz) * s); }
        ax = bx; ay = by; az = bz;

        // boundary sample for u=3: lane<63 from own window; lane 63 from next chunk
        WAITV(0);                              // chunk c+1 landed
        float rx = Wd.x, ry = Wd.y, rz = Wd.z, t4 = Tb.x;
        if (c < NCHUNK - 1) {
            const float4 Xg = ((const float4*)oth)[0];   // uniform addr -> broadcast
            const float  Xt = oth[GFL];
            if (lane == 63) { rx = Xg.x; ry = Xg.y; rz = Xg.z; t4 = Xt; }
        } else {
            if (lane == 63) t4 = Ta.w;         // global step 2047: dt = 0 pad
        }
        gfv(rx, ry, rz, bx, by, bz);
        { const float s = 0.25f * (t4 - Ta.w);
          q = qmul1(q, (ax + bx) * s, (ay + by) * s, (az + bz) * s); }

        // normalize chunk product (norm >= 1)
        {
            const float n2  = fmaf(q.w, q.w, fmaf(q.x, q.x, fmaf(q.y, q.y, q.z * q.z)));
            const float inv = 1.0f / sqrtf(n2);
            q.w *= inv; q.x *= inv; q.y *= inv; q.z *= inv;
        }

        // ordered 64-lane suffix-product butterfly: lane 0 gets P_0 (x) ... (x) P_63
        #pragma unroll
        for (int sft = 1; sft < 64; sft <<= 1) {
            Q o;
            o.w = __shfl_down(q.w, sft);
            o.x = __shfl_down(q.x, sft);
            o.y = __shfl_down(q.y, sft);
            o.z = __shfl_down(q.z, sft);
            q = qmul(q, o);
        }
        acc = qmul(acc, q);                    // meaningful in lane 0 only

        // prefetch chunk c+2 into cur (its reads are all done; DMA lands later)
        if (c < NCHUNK - 2) issue(c + 2, cur);
    }

    if (lane == 0) {
        const float4 s0 = ((const float4*)(sq + (size_t)row * 4))[0];
        const Q q0 = {s0.x, s0.y, s0.z, s0.w};
        Q qf = qmul(q0, acc);
        const float n   = sqrtf(fmaf(qf.w, qf.w, fmaf(qf.x, qf.x, fmaf(qf.y, qf.y, qf.z * qf.z))));
        const float inv = 1.0f / fmaxf(n, 1e-12f);
        float4 o;
        o.x = qf.w * inv; o.y = qf.x * inv; o.z = qf.y * inv; o.w = qf.z * inv;
        ((float4*)(out + (size_t)row * 4))[0] = o;
    }
}

extern "C" void kernel_launch(void* const* d_in, const int* in_sizes, int n_in,
                              void* d_out, int out_size, void* d_ws, size_t ws_size,
                              hipStream_t stream) {
    const float* ts   = (const float*)d_in[0];  // timestampns_set (B, CNT)
    const float* gyro = (const float*)d_in[1];  // gyro_set (B, CNT, 3)
    const float* sq   = (const float*)d_in[2];  // start_quat (B, 4)
    const float* W1   = (const float*)d_in[3];
    const float* b1   = (const float*)d_in[4];
    const float* a1   = (const float*)d_in[5];
    const float* W2   = (const float*)d_in[6];
    const float* b2   = (const float*)d_in[7];
    const float* a2   = (const float*)d_in[8];
    float* out = (float*)d_out;

    const int B = in_sizes[0] / CNT;  // 4096
    const int grid = (B + RPB - 1) / RPB;

    quat_scan_kernel<<<grid, TPB, 0, stream>>>(ts, gyro, sq, W1, b1, a1, W2, b2, a2, out, B);
}